// Round 1
// baseline (632.284 us; speedup 1.0000x reference)
//
#include <hip/hip_runtime.h>
#include <cstdint>
#include <cstddef>

typedef __bf16 bf16x8 __attribute__((ext_vector_type(8)));
typedef float f32x4 __attribute__((ext_vector_type(4)));
static_assert(sizeof(bf16x8) == 16, "bf16x8 must be 16B");
static_assert(sizeof(f32x4) == 16, "f32x4 must be 16B");

#define MFMA16(a, b, c) __builtin_amdgcn_mfma_f32_16x16x32_bf16((a), (b), (c), 0, 0, 0)

__device__ __forceinline__ void gload_lds16(const void* g, void* l) {
  __builtin_amdgcn_global_load_lds(
      (const __attribute__((address_space(1))) void*)g,
      (__attribute__((address_space(3))) void*)l, 16, 0, 0);
}

// ---------------------------------------------------------------- conv x -> bf16
__global__ __launch_bounds__(256) void conv_x_kernel(const float* __restrict__ in,
                                                     __bf16* __restrict__ out) {
  size_t i = ((size_t)blockIdx.x * 256 + threadIdx.x) * 4;
  const float4 v = *(const float4*)(in + i);
  out[i + 0] = (__bf16)v.x;
  out[i + 1] = (__bf16)v.y;
  out[i + 2] = (__bf16)v.z;
  out[i + 3] = (__bf16)v.w;
}

// ------------------------------------------- transpose fp32 [K][N] -> bf16 [N][K]
__global__ __launch_bounds__(256) void transpose_conv_kernel(const float* __restrict__ in,
                                                             __bf16* __restrict__ out,
                                                             int K, int N) {
  __shared__ float tile[32][33];
  const int n0 = blockIdx.x * 32, k0 = blockIdx.y * 32;
  const int tx = threadIdx.x, ty = threadIdx.y;  // (32, 8)
#pragma unroll
  for (int i = 0; i < 4; ++i)
    tile[ty * 4 + i][tx] = in[(size_t)(k0 + ty * 4 + i) * N + n0 + tx];
  __syncthreads();
#pragma unroll
  for (int i = 0; i < 4; ++i)
    out[(size_t)(n0 + ty * 4 + i) * K + k0 + tx] = (__bf16)tile[tx][ty * 4 + i];
}

// ------------------------------------------------------- rel-pos bias gather
// bias[h][i][j] = table[ids[i*256+j]*12 + h]
__global__ __launch_bounds__(256) void bias_gather_kernel(const float* __restrict__ table,
                                                          const int* __restrict__ ids,
                                                          float* __restrict__ bias) {
  const int idx = blockIdx.x * 256 + threadIdx.x;  // < 12*65536
  const int h = idx >> 16, ij = idx & 65535;
  bias[idx] = table[ids[ij] * 12 + h];
}

// ---------------------------------------------------------------- bf16 GEMM
// C[M,N] = A[M,K] * B[K,N], with Bt = B^T ([N][K], k-contiguous).
// 128x128 tile, BK=32, 4 waves each 64x64 (4x4 of 16x16x32 MFMA).
// LDS layout XOR-swizzled: elem (row, k) stored at row*32 + ((k>>3) ^ ((row>>1)&3))*8 + (k&7)
// -> global_load_lds stays lane-contiguous AND ds_read_b128 frag reads are <=2-way bank aliased.
// MODE 0: QKV epilogue -> scatter Q(scaled)/K bf16 [b,h,n,d] and V^T bf16 [b,h,d,n]
// MODE 1: plain fp32 C + bias -> out
template <int MODE>
__global__ __launch_bounds__(256) void gemm_kernel(const __bf16* __restrict__ A,
                                                   const __bf16* __restrict__ Bt,
                                                   const float* __restrict__ bias,
                                                   void* __restrict__ out0,
                                                   __bf16* __restrict__ kbuf,
                                                   __bf16* __restrict__ vtbuf,
                                                   const int M, const int N, const int K) {
  __shared__ __bf16 smem[2 * 128 * 32];
  const int tid = threadIdx.x;
  const int lane = tid & 63, w = tid >> 6;
  const int m16 = lane & 15, q4 = lane >> 4;
  const int wm = w & 1, wn = w >> 1;
  const int m0 = blockIdx.y * 128, n0 = blockIdx.x * 128;

  // staging: wave w covers tile rows [w*32, w*32+32), two 16-row instructions
  const int srow0 = w * 32 + (lane >> 2);
  const int srow1 = srow0 + 16;
  const int kg0 = (lane & 3) ^ ((srow0 >> 1) & 3);
  const int kg1 = (lane & 3) ^ ((srow1 >> 1) & 3);
  const __bf16* ag0 = A + (size_t)(m0 + srow0) * K + kg0 * 8;
  const __bf16* ag1 = A + (size_t)(m0 + srow1) * K + kg1 * 8;
  const __bf16* bg0 = Bt + (size_t)(n0 + srow0) * K + kg0 * 8;
  const __bf16* bg1 = Bt + (size_t)(n0 + srow1) * K + kg1 * 8;
  __bf16* lA0 = &smem[(w * 32) * 32];
  __bf16* lA1 = &smem[(w * 32 + 16) * 32];
  __bf16* lB0 = &smem[4096 + (w * 32) * 32];
  __bf16* lB1 = &smem[4096 + (w * 32 + 16) * 32];

  // fixed per-lane frag offsets (elements)
  int aoff[4], boff[4];
#pragma unroll
  for (int t = 0; t < 4; ++t) {
    const int ra = wm * 64 + t * 16 + m16;
    aoff[t] = ra * 32 + ((q4 ^ ((ra >> 1) & 3)) * 8);
    const int rb = wn * 64 + t * 16 + m16;
    boff[t] = 4096 + rb * 32 + ((q4 ^ ((rb >> 1) & 3)) * 8);
  }

  f32x4 acc[4][4] = {};
  const int ksteps = K >> 5;
  for (int kt = 0; kt < ksteps; ++kt) {
    gload_lds16(ag0, lA0);
    gload_lds16(ag1, lA1);
    gload_lds16(bg0, lB0);
    gload_lds16(bg1, lB1);
    ag0 += 32; ag1 += 32; bg0 += 32; bg1 += 32;
    __syncthreads();  // drain vmcnt: staging complete
    bf16x8 af[4], bf[4];
#pragma unroll
    for (int i = 0; i < 4; ++i) af[i] = *(const bf16x8*)&smem[aoff[i]];
#pragma unroll
    for (int i = 0; i < 4; ++i) bf[i] = *(const bf16x8*)&smem[boff[i]];
#pragma unroll
    for (int mt = 0; mt < 4; ++mt)
#pragma unroll
      for (int nt = 0; nt < 4; ++nt) acc[mt][nt] = MFMA16(af[mt], bf[nt], acc[mt][nt]);
    __syncthreads();  // all reads done before next stage overwrites
  }

  const int gnb = n0 + wn * 64;
  const int gmb = m0 + wm * 64;
  if (MODE == 0) {
    __bf16* qbuf = (__bf16*)out0;
    const int which = n0 / 768;  // block-uniform (128 | 768)
#pragma unroll
    for (int nt = 0; nt < 4; ++nt) {
      const int gn = gnb + nt * 16 + m16;
      const float bn = bias[gn];
      const int rem = gn - which * 768;
      const int hh = rem >> 6, dd = rem & 63;
#pragma unroll
      for (int mt = 0; mt < 4; ++mt) {
#pragma unroll
        for (int r = 0; r < 4; ++r) {
          const int gm = gmb + mt * 16 + q4 * 4 + r;  // C row = quad*4+reg (m89)
          const int bi = gm >> 8, tok = gm & 255;
          const float v = acc[mt][nt][r] + bn;
          const size_t hb = (size_t)bi * 12 + hh;
          if (which == 0)
            qbuf[(hb * 256 + tok) * 64 + dd] = (__bf16)(v * 0.125f);  // pre-scale Q
          else if (which == 1)
            kbuf[(hb * 256 + tok) * 64 + dd] = (__bf16)v;
          else
            vtbuf[(hb * 64 + dd) * 256 + tok] = (__bf16)v;
        }
      }
    }
  } else {
    float* out = (float*)out0;
#pragma unroll
    for (int nt = 0; nt < 4; ++nt) {
      const int gn = gnb + nt * 16 + m16;
      const float bn = bias[gn];
#pragma unroll
      for (int mt = 0; mt < 4; ++mt)
#pragma unroll
        for (int r = 0; r < 4; ++r) {
          const int gm = gmb + mt * 16 + q4 * 4 + r;
          out[(size_t)gm * N + gn] = acc[mt][nt][r] + bn;
        }
    }
  }
}

// ---------------------------------------------------------------- attention
// grid (2, 12, 128): half, h, b. 4 waves; wave w owns 32 Q-rows; full 256-key rows.
__global__ __launch_bounds__(256) void attn_kernel(const __bf16* __restrict__ qb,
                                                   const __bf16* __restrict__ kb,
                                                   const __bf16* __restrict__ vtb,
                                                   const float* __restrict__ biasg,
                                                   __bf16* __restrict__ o_ws) {
  __shared__ __bf16 plds[4][32 * 72];  // per-wave P chunk, 72-elem stride (16B-aligned rows)
  const int tid = threadIdx.x;
  const int lane = tid & 63, w = tid >> 6;
  const int m16 = lane & 15, q4 = lane >> 4;
  const int h = blockIdx.y, b = blockIdx.z;
  const size_t bh = (size_t)b * 12 + h;
  const __bf16* Q = qb + bh * (256 * 64);
  const __bf16* Kp = kb + bh * (256 * 64);
  const __bf16* Vt = vtb + bh * (64 * 256);
  const float* Bh = biasg + (size_t)h * 65536;
  const int qbase = blockIdx.x * 128 + w * 32;

  // Q frags (A-layout): row = lane&15, k = quad*8+j
  bf16x8 qf[2][2];
#pragma unroll
  for (int rb = 0; rb < 2; ++rb)
#pragma unroll
    for (int t = 0; t < 2; ++t)
      qf[rb][t] = *(const bf16x8*)(Q + (size_t)(qbase + rb * 16 + m16) * 64 + t * 32 + q4 * 8);

  // S = (Q*scale) K^T  (Q pre-scaled in GEMM epilogue)
  f32x4 s[2][16];
#pragma unroll
  for (int c = 0; c < 16; ++c) {
    const bf16x8 kf0 = *(const bf16x8*)(Kp + (size_t)(c * 16 + m16) * 64 + q4 * 8);
    const bf16x8 kf1 = *(const bf16x8*)(Kp + (size_t)(c * 16 + m16) * 64 + 32 + q4 * 8);
#pragma unroll
    for (int rb = 0; rb < 2; ++rb) {
      f32x4 z = {0.f, 0.f, 0.f, 0.f};
      z = MFMA16(qf[rb][0], kf0, z);
      s[rb][c] = MFMA16(qf[rb][1], kf1, z);
    }
  }

  // + rel-pos bias (fp32, L2-resident table)
#pragma unroll
  for (int rb = 0; rb < 2; ++rb)
#pragma unroll
    for (int c = 0; c < 16; ++c)
#pragma unroll
      for (int r = 0; r < 4; ++r)
        s[rb][c][r] += Bh[(size_t)(qbase + rb * 16 + q4 * 4 + r) * 256 + c * 16 + m16];

  // full-row softmax; row owned by the 16 lanes sharing lane>>4
  float linv[2][4];
#pragma unroll
  for (int rb = 0; rb < 2; ++rb)
#pragma unroll
    for (int r = 0; r < 4; ++r) {
      float mx = s[rb][0][r];
#pragma unroll
      for (int c = 1; c < 16; ++c) mx = fmaxf(mx, s[rb][c][r]);
      mx = fmaxf(mx, __shfl_xor(mx, 1));
      mx = fmaxf(mx, __shfl_xor(mx, 2));
      mx = fmaxf(mx, __shfl_xor(mx, 4));
      mx = fmaxf(mx, __shfl_xor(mx, 8));
      float sum = 0.f;
#pragma unroll
      for (int c = 0; c < 16; ++c) {
        const float p = exp2f((s[rb][c][r] - mx) * 1.4426950408889634f);
        s[rb][c][r] = p;
        sum += p;
      }
      sum += __shfl_xor(sum, 1);
      sum += __shfl_xor(sum, 2);
      sum += __shfl_xor(sum, 4);
      sum += __shfl_xor(sum, 8);
      linv[rb][r] = 1.f / sum;
    }

  // O = P V, P round-trips through per-wave LDS (C-layout -> A-layout), 64-key chunks
  f32x4 o[2][4] = {};
  __bf16* P = &plds[w][0];
#pragma unroll
  for (int ch = 0; ch < 4; ++ch) {
#pragma unroll
    for (int rb = 0; rb < 2; ++rb)
#pragma unroll
      for (int cc = 0; cc < 4; ++cc)
#pragma unroll
        for (int r = 0; r < 4; ++r)
          P[(rb * 16 + q4 * 4 + r) * 72 + cc * 16 + m16] = (__bf16)s[rb][ch * 4 + cc][r];
    // same-wave LDS RAW/WAR: compiler inserts lgkmcnt waits; no barrier needed
#pragma unroll
    for (int kt = 0; kt < 2; ++kt) {
      bf16x8 pf[2];
#pragma unroll
      for (int rb = 0; rb < 2; ++rb)
        pf[rb] = *(const bf16x8*)(P + (rb * 16 + m16) * 72 + kt * 32 + q4 * 8);
#pragma unroll
      for (int dt = 0; dt < 4; ++dt) {
        const bf16x8 vf =
            *(const bf16x8*)(Vt + (size_t)(dt * 16 + m16) * 256 + ch * 64 + kt * 32 + q4 * 8);
#pragma unroll
        for (int rb = 0; rb < 2; ++rb) o[rb][dt] = MFMA16(pf[rb], vf, o[rb][dt]);
      }
    }
  }

  // normalize + store bf16 [b*n][h*64+d] for the out-proj GEMM
#pragma unroll
  for (int rb = 0; rb < 2; ++rb)
#pragma unroll
    for (int dt = 0; dt < 4; ++dt)
#pragma unroll
      for (int r = 0; r < 4; ++r) {
        const float v = o[rb][dt][r] * linv[rb][r];
        const size_t row = (size_t)b * 256 + qbase + rb * 16 + q4 * 4 + r;
        o_ws[row * 768 + h * 64 + dt * 16 + m16] = (__bf16)v;
      }
}

// ---------------------------------------------------------------- launch
extern "C" void kernel_launch(void* const* d_in, const int* in_sizes, int n_in,
                              void* d_out, int out_size, void* d_ws, size_t ws_size,
                              hipStream_t stream) {
  const float* x = (const float*)d_in[0];      // [128,256,768]
  const float* Wqkv = (const float*)d_in[1];   // [768,2304]
  const float* bqkv = (const float*)d_in[2];   // [2304]
  const float* Wout = (const float*)d_in[3];   // [768,768]
  const float* bout = (const float*)d_in[4];   // [768]
  const float* table = (const float*)d_in[5];  // [961,12]
  const int* ids = (const int*)d_in[6];        // [65536]
  float* out = (float*)d_out;

  char* ws = (char*)d_ws;
  // workspace layout (all 256B-aligned); x_bf16 region is reused as o_ws after GEMM1
  __bf16* xbf = (__bf16*)ws;                             // 50331648 B (alias: o_ws)
  __bf16* wqkvt = (__bf16*)(ws + 50331648);              //  3538944 B
  __bf16* woutt = (__bf16*)(ws + 53870592);              //  1179648 B
  __bf16* qbuf = (__bf16*)(ws + 55050240);               // 50331648 B
  __bf16* kbuf = (__bf16*)(ws + 105381888);              // 50331648 B
  __bf16* vtbuf = (__bf16*)(ws + 155713536);             // 50331648 B
  float* biasg = (float*)(ws + 206045184);               //  3145728 B  (total 209190912)

  conv_x_kernel<<<24576, 256, 0, stream>>>(x, xbf);
  transpose_conv_kernel<<<dim3(72, 24), dim3(32, 8), 0, stream>>>(Wqkv, wqkvt, 768, 2304);
  transpose_conv_kernel<<<dim3(24, 24), dim3(32, 8), 0, stream>>>(Wout, woutt, 768, 768);
  bias_gather_kernel<<<3072, 256, 0, stream>>>(table, ids, biasg);
  gemm_kernel<0><<<dim3(18, 256), 256, 0, stream>>>(xbf, wqkvt, bqkv, qbuf, kbuf, vtbuf,
                                                    32768, 2304, 768);
  attn_kernel<<<dim3(2, 12, 128), 256, 0, stream>>>(qbuf, kbuf, vtbuf, biasg, xbf /*o_ws*/);
  gemm_kernel<1><<<dim3(6, 256), 256, 0, stream>>>(xbf, woutt, bout, out, nullptr, nullptr,
                                                   32768, 768, 768);
}

// Round 2
// 600.688 us; speedup vs baseline: 1.0526x; 1.0526x over previous
//
#include <hip/hip_runtime.h>
#include <cstdint>
#include <cstddef>

typedef __bf16 bf16x8 __attribute__((ext_vector_type(8)));
typedef __bf16 bf16x4 __attribute__((ext_vector_type(4)));
typedef float f32x4 __attribute__((ext_vector_type(4)));
static_assert(sizeof(bf16x8) == 16, "bf16x8 must be 16B");
static_assert(sizeof(bf16x4) == 8, "bf16x4 must be 8B");
static_assert(sizeof(f32x4) == 16, "f32x4 must be 16B");

#define MFMA16(a, b, c) __builtin_amdgcn_mfma_f32_16x16x32_bf16((a), (b), (c), 0, 0, 0)

__device__ __forceinline__ void gload_lds16(const void* g, void* l) {
  __builtin_amdgcn_global_load_lds(
      (const __attribute__((address_space(1))) void*)g,
      (__attribute__((address_space(3))) void*)l, 16, 0, 0);
}

// ---------------------------------------------------------------- conv x -> bf16
__global__ __launch_bounds__(256) void conv_x_kernel(const float* __restrict__ in,
                                                     __bf16* __restrict__ out) {
  size_t i = ((size_t)blockIdx.x * 256 + threadIdx.x) * 4;
  const float4 v = *(const float4*)(in + i);
  out[i + 0] = (__bf16)v.x;
  out[i + 1] = (__bf16)v.y;
  out[i + 2] = (__bf16)v.z;
  out[i + 3] = (__bf16)v.w;
}

// ------------------------------------------- transpose fp32 [K][N] -> bf16 [N][K]
__global__ __launch_bounds__(256) void transpose_conv_kernel(const float* __restrict__ in,
                                                             __bf16* __restrict__ out,
                                                             int K, int N) {
  __shared__ float tile[32][33];
  const int n0 = blockIdx.x * 32, k0 = blockIdx.y * 32;
  const int tx = threadIdx.x, ty = threadIdx.y;  // (32, 8)
#pragma unroll
  for (int i = 0; i < 4; ++i)
    tile[ty * 4 + i][tx] = in[(size_t)(k0 + ty * 4 + i) * N + n0 + tx];
  __syncthreads();
#pragma unroll
  for (int i = 0; i < 4; ++i)
    out[(size_t)(n0 + ty * 4 + i) * K + k0 + tx] = (__bf16)tile[tx][ty * 4 + i];
}

// ------------------------------------------------------- rel-pos bias gather
__global__ __launch_bounds__(256) void bias_gather_kernel(const float* __restrict__ table,
                                                          const int* __restrict__ ids,
                                                          float* __restrict__ bias) {
  const int idx = blockIdx.x * 256 + threadIdx.x;  // < 12*65536
  const int h = idx >> 16, ij = idx & 65535;
  bias[idx] = table[ids[ij] * 12 + h];
}

// ---------------------------------------------------------------- bf16 GEMM
// C[M,N] = A[M,K] * Bt^T. 128x128 tile, BK=64 (32 MFMA per barrier pair), 4 waves
// each 64x64. LDS XOR-swizzle: elem (row,k) at row*64 + ((k>>3)^(row&7))*8 + (k&7)
// -> staging stays lane-contiguous (HW base+lane*16) AND frag ds_read_b128 is
// bank-balanced (verified round 1: SQ_LDS_BANK_CONFLICT == 0 with same scheme).
// MODE 0: TRANS (acc=C^T) -> packed 8-B scatter of Q(scaled)/K into [b,h,n,d]
// MODE 1: TRANS (acc=C^T) -> fp32 row-major C + bias (reg r runs along gn: f32x4 store)
// MODE 2: no-TRANS (acc=C) -> packed 8-B scatter of V^T into [b,h,d,n] (reg r runs along tok)
template <int MODE>
__global__ __launch_bounds__(256) void gemm_kernel(const __bf16* __restrict__ A,
                                                   const __bf16* __restrict__ Bt,
                                                   const float* __restrict__ bias,
                                                   void* __restrict__ out0,
                                                   __bf16* __restrict__ kbuf,
                                                   const int M, const int N, const int K) {
  constexpr bool TRANS = (MODE != 2);
  __shared__ __bf16 smem[2 * 128 * 64];  // 32 KB
  const int tid = threadIdx.x;
  const int lane = tid & 63, w = tid >> 6;
  const int m16 = lane & 15, q4 = lane >> 4;
  const int wm = w & 1, wn = w >> 1;
  const int m0 = blockIdx.y * 128, n0 = blockIdx.x * 128;

  // staging: wave w covers tile rows [w*32, w*32+32), 4 insts x 8 rows x 128 B
  const __bf16* ag[4];
  const __bf16* bg[4];
  __bf16* la[4];
  __bf16* lb[4];
#pragma unroll
  for (int i = 0; i < 4; ++i) {
    const int row = w * 32 + i * 8 + (lane >> 3);
    const int col = ((lane & 7) ^ (row & 7)) * 8;
    ag[i] = A + (size_t)(m0 + row) * K + col;
    bg[i] = Bt + (size_t)(n0 + row) * K + col;
    la[i] = &smem[(w * 32 + i * 8) * 64];
    lb[i] = &smem[8192 + (w * 32 + i * 8) * 64];
  }

  int aoff[4][2], boff[4][2];
#pragma unroll
  for (int t = 0; t < 4; ++t)
#pragma unroll
    for (int kh = 0; kh < 2; ++kh) {
      const int ra = wm * 64 + t * 16 + m16;
      aoff[t][kh] = ra * 64 + (((kh * 4 + q4) ^ (ra & 7)) * 8);
      const int rb = wn * 64 + t * 16 + m16;
      boff[t][kh] = 8192 + rb * 64 + (((kh * 4 + q4) ^ (rb & 7)) * 8);
    }

  f32x4 acc[4][4] = {};
  const int ksteps = K >> 6;
  for (int kt = 0; kt < ksteps; ++kt) {
#pragma unroll
    for (int i = 0; i < 4; ++i) gload_lds16(ag[i], la[i]);
#pragma unroll
    for (int i = 0; i < 4; ++i) gload_lds16(bg[i], lb[i]);
#pragma unroll
    for (int i = 0; i < 4; ++i) { ag[i] += 64; bg[i] += 64; }
    __syncthreads();  // staging complete
    bf16x8 af[4][2], bfr[4][2];
#pragma unroll
    for (int t = 0; t < 4; ++t)
#pragma unroll
      for (int kh = 0; kh < 2; ++kh) {
        af[t][kh] = *(const bf16x8*)&smem[aoff[t][kh]];
        bfr[t][kh] = *(const bf16x8*)&smem[boff[t][kh]];
      }
#pragma unroll
    for (int kh = 0; kh < 2; ++kh)
#pragma unroll
      for (int i = 0; i < 4; ++i)
#pragma unroll
        for (int j = 0; j < 4; ++j) {
          if (TRANS)
            acc[i][j] = MFMA16(bfr[i][kh], af[j][kh], acc[i][j]);  // C^T: rows<->gn
          else
            acc[i][j] = MFMA16(af[i][kh], bfr[j][kh], acc[i][j]);  // C: rows<->gm
        }
    __syncthreads();  // reads done before next stage overwrites
  }

  const int gnb = n0 + wn * 64;
  const int gmb = m0 + wm * 64;

  if (MODE == 0) {
    // acc[i][j][r]: gn = gnb + i*16 + q4*4 + r, gm = gmb + j*16 + m16
    __bf16* qb = (__bf16*)out0;
    const int which = (n0 >= 768);
    __bf16* dst = which ? kbuf : qb;
    const float qscale = which ? 1.0f : 0.125f;
    const int bi = gmb >> 8;
    const int tokb = gmb & 255;
#pragma unroll
    for (int i = 0; i < 4; ++i) {
      const int gn0 = gnb + i * 16 + q4 * 4;
      const f32x4 bn = *(const f32x4*)&bias[gn0];
      const int rem0 = gn0 - which * 768;
      const int hh = rem0 >> 6, dd0 = rem0 & 63;
      __bf16* base = dst + ((size_t)bi * 12 + hh) * 16384 + dd0;
#pragma unroll
      for (int j = 0; j < 4; ++j) {
        const int tok = tokb + j * 16 + m16;
        bf16x4 pk;
#pragma unroll
        for (int r = 0; r < 4; ++r) pk[r] = (__bf16)((acc[i][j][r] + bn[r]) * qscale);
        *(bf16x4*)(base + (size_t)tok * 64) = pk;
      }
    }
  } else if (MODE == 2) {
    // acc[i][j][r]: gm = gmb + i*16 + q4*4 + r, gn = gnb + j*16 + m16 (gn local in [0,768))
    __bf16* vt = (__bf16*)out0;
    const int bi = gmb >> 8;
    const int tokb = gmb & 255;
#pragma unroll
    for (int j = 0; j < 4; ++j) {
      const int gn = gnb + j * 16 + m16;
      const float bn = bias[gn];
      const int hh = gn >> 6, dd = gn & 63;
      __bf16* base = vt + (((size_t)bi * 12 + hh) * 64 + dd) * 256;
#pragma unroll
      for (int i = 0; i < 4; ++i) {
        const int tok0 = tokb + i * 16 + q4 * 4;
        bf16x4 pk;
#pragma unroll
        for (int r = 0; r < 4; ++r) pk[r] = (__bf16)(acc[i][j][r] + bn);
        *(bf16x4*)(base + tok0) = pk;
      }
    }
  } else {
    // acc[i][j][r]: gn = gnb + i*16 + q4*4 + r, gm = gmb + j*16 + m16
    float* out = (float*)out0;
#pragma unroll
    for (int i = 0; i < 4; ++i) {
      const int gn0 = gnb + i * 16 + q4 * 4;
      const f32x4 bn = *(const f32x4*)&bias[gn0];
#pragma unroll
      for (int j = 0; j < 4; ++j) {
        const int gm = gmb + j * 16 + m16;
        f32x4 v;
#pragma unroll
        for (int r = 0; r < 4; ++r) v[r] = acc[i][j][r] + bn[r];
        *(f32x4*)(out + (size_t)gm * N + gn0) = v;
      }
    }
  }
}

// ---------------------------------------------------------------- attention
// grid (2, 12, 128): half, h, b. 4 waves; wave w owns 32 Q-rows; full 256-key rows.
__global__ __launch_bounds__(256) void attn_kernel(const __bf16* __restrict__ qb,
                                                   const __bf16* __restrict__ kb,
                                                   const __bf16* __restrict__ vtb,
                                                   const float* __restrict__ biasg,
                                                   __bf16* __restrict__ o_ws) {
  __shared__ __bf16 plds[4][32 * 72];  // per-wave P chunk, 72-elem stride
  const int tid = threadIdx.x;
  const int lane = tid & 63, w = tid >> 6;
  const int m16 = lane & 15, q4 = lane >> 4;
  const int h = blockIdx.y, b = blockIdx.z;
  const size_t bh = (size_t)b * 12 + h;
  const __bf16* Q = qb + bh * (256 * 64);
  const __bf16* Kp = kb + bh * (256 * 64);
  const __bf16* Vt = vtb + bh * (64 * 256);
  const float* Bh = biasg + (size_t)h * 65536;
  const int qbase = blockIdx.x * 128 + w * 32;

  bf16x8 qf[2][2];
#pragma unroll
  for (int rb = 0; rb < 2; ++rb)
#pragma unroll
    for (int t = 0; t < 2; ++t)
      qf[rb][t] = *(const bf16x8*)(Q + (size_t)(qbase + rb * 16 + m16) * 64 + t * 32 + q4 * 8);

  f32x4 s[2][16];
#pragma unroll
  for (int c = 0; c < 16; ++c) {
    const bf16x8 kf0 = *(const bf16x8*)(Kp + (size_t)(c * 16 + m16) * 64 + q4 * 8);
    const bf16x8 kf1 = *(const bf16x8*)(Kp + (size_t)(c * 16 + m16) * 64 + 32 + q4 * 8);
#pragma unroll
    for (int rb = 0; rb < 2; ++rb) {
      f32x4 z = {0.f, 0.f, 0.f, 0.f};
      z = MFMA16(qf[rb][0], kf0, z);
      s[rb][c] = MFMA16(qf[rb][1], kf1, z);
    }
  }

#pragma unroll
  for (int rb = 0; rb < 2; ++rb)
#pragma unroll
    for (int c = 0; c < 16; ++c)
#pragma unroll
      for (int r = 0; r < 4; ++r)
        s[rb][c][r] += Bh[(size_t)(qbase + rb * 16 + q4 * 4 + r) * 256 + c * 16 + m16];

  float linv[2][4];
#pragma unroll
  for (int rb = 0; rb < 2; ++rb)
#pragma unroll
    for (int r = 0; r < 4; ++r) {
      float mx = s[rb][0][r];
#pragma unroll
      for (int c = 1; c < 16; ++c) mx = fmaxf(mx, s[rb][c][r]);
      mx = fmaxf(mx, __shfl_xor(mx, 1));
      mx = fmaxf(mx, __shfl_xor(mx, 2));
      mx = fmaxf(mx, __shfl_xor(mx, 4));
      mx = fmaxf(mx, __shfl_xor(mx, 8));
      float sum = 0.f;
#pragma unroll
      for (int c = 0; c < 16; ++c) {
        const float p = exp2f((s[rb][c][r] - mx) * 1.4426950408889634f);
        s[rb][c][r] = p;
        sum += p;
      }
      sum += __shfl_xor(sum, 1);
      sum += __shfl_xor(sum, 2);
      sum += __shfl_xor(sum, 4);
      sum += __shfl_xor(sum, 8);
      linv[rb][r] = 1.f / sum;
    }

  f32x4 o[2][4] = {};
  __bf16* P = &plds[w][0];
#pragma unroll
  for (int ch = 0; ch < 4; ++ch) {
#pragma unroll
    for (int rb = 0; rb < 2; ++rb)
#pragma unroll
      for (int cc = 0; cc < 4; ++cc)
#pragma unroll
        for (int r = 0; r < 4; ++r)
          P[(rb * 16 + q4 * 4 + r) * 72 + cc * 16 + m16] = (__bf16)s[rb][ch * 4 + cc][r];
#pragma unroll
    for (int kt = 0; kt < 2; ++kt) {
      bf16x8 pf[2];
#pragma unroll
      for (int rb = 0; rb < 2; ++rb)
        pf[rb] = *(const bf16x8*)(P + (rb * 16 + m16) * 72 + kt * 32 + q4 * 8);
#pragma unroll
      for (int dt = 0; dt < 4; ++dt) {
        const bf16x8 vf =
            *(const bf16x8*)(Vt + (size_t)(dt * 16 + m16) * 256 + ch * 64 + kt * 32 + q4 * 8);
#pragma unroll
        for (int rb = 0; rb < 2; ++rb) o[rb][dt] = MFMA16(pf[rb], vf, o[rb][dt]);
      }
    }
  }

#pragma unroll
  for (int rb = 0; rb < 2; ++rb)
#pragma unroll
    for (int dt = 0; dt < 4; ++dt)
#pragma unroll
      for (int r = 0; r < 4; ++r) {
        const float v = o[rb][dt][r] * linv[rb][r];
        const size_t row = (size_t)b * 256 + qbase + rb * 16 + q4 * 4 + r;
        o_ws[row * 768 + h * 64 + dt * 16 + m16] = (__bf16)v;
      }
}

// ---------------------------------------------------------------- launch
extern "C" void kernel_launch(void* const* d_in, const int* in_sizes, int n_in,
                              void* d_out, int out_size, void* d_ws, size_t ws_size,
                              hipStream_t stream) {
  const float* x = (const float*)d_in[0];      // [128,256,768]
  const float* Wqkv = (const float*)d_in[1];   // [768,2304]
  const float* bqkv = (const float*)d_in[2];   // [2304]
  const float* Wout = (const float*)d_in[3];   // [768,768]
  const float* bout = (const float*)d_in[4];   // [768]
  const float* table = (const float*)d_in[5];  // [961,12]
  const int* ids = (const int*)d_in[6];        // [65536]
  float* out = (float*)d_out;

  char* ws = (char*)d_ws;
  __bf16* xbf = (__bf16*)ws;                             // 50331648 B (alias: o_ws)
  __bf16* wqkvt = (__bf16*)(ws + 50331648);              //  3538944 B
  __bf16* woutt = (__bf16*)(ws + 53870592);              //  1179648 B
  __bf16* qbuf = (__bf16*)(ws + 55050240);               // 50331648 B
  __bf16* kbuf = (__bf16*)(ws + 105381888);              // 50331648 B
  __bf16* vtbuf = (__bf16*)(ws + 155713536);             // 50331648 B
  float* biasg = (float*)(ws + 206045184);               //  3145728 B

  conv_x_kernel<<<24576, 256, 0, stream>>>(x, xbf);
  transpose_conv_kernel<<<dim3(72, 24), dim3(32, 8), 0, stream>>>(Wqkv, wqkvt, 768, 2304);
  transpose_conv_kernel<<<dim3(24, 24), dim3(32, 8), 0, stream>>>(Wout, woutt, 768, 768);
  bias_gather_kernel<<<3072, 256, 0, stream>>>(table, ids, biasg);
  // QK part: N in [0,1536)
  gemm_kernel<0><<<dim3(12, 256), 256, 0, stream>>>(xbf, wqkvt, bqkv, qbuf, kbuf,
                                                    32768, 2304, 768);
  // V part: N in [1536,2304) -> V^T scatter
  gemm_kernel<2><<<dim3(6, 256), 256, 0, stream>>>(xbf, wqkvt + (size_t)1536 * 768,
                                                   bqkv + 1536, vtbuf, nullptr,
                                                   32768, 768, 768);
  attn_kernel<<<dim3(2, 12, 128), 256, 0, stream>>>(qbuf, kbuf, vtbuf, biasg, xbf /*o_ws*/);
  gemm_kernel<1><<<dim3(6, 256), 256, 0, stream>>>(xbf, woutt, bout, out, nullptr,
                                                   32768, 768, 768);
}

// Round 3
// 528.206 us; speedup vs baseline: 1.1970x; 1.1372x over previous
//
#include <hip/hip_runtime.h>
#include <cstdint>
#include <cstddef>

typedef __bf16 bf16x8 __attribute__((ext_vector_type(8)));
typedef __bf16 bf16x4 __attribute__((ext_vector_type(4)));
typedef float f32x4 __attribute__((ext_vector_type(4)));
static_assert(sizeof(bf16x8) == 16, "bf16x8 must be 16B");
static_assert(sizeof(bf16x4) == 8, "bf16x4 must be 8B");
static_assert(sizeof(f32x4) == 16, "f32x4 must be 16B");

#define MFMA16(a, b, c) __builtin_amdgcn_mfma_f32_16x16x32_bf16((a), (b), (c), 0, 0, 0)

__device__ __forceinline__ void gload_lds16(const void* g, void* l) {
  __builtin_amdgcn_global_load_lds(
      (const __attribute__((address_space(1))) void*)g,
      (__attribute__((address_space(3))) void*)l, 16, 0, 0);
}

// ---------------------------------------------------------------- conv x -> bf16
__global__ __launch_bounds__(256) void conv_x_kernel(const float* __restrict__ in,
                                                     __bf16* __restrict__ out) {
  size_t i = ((size_t)blockIdx.x * 256 + threadIdx.x) * 4;
  const float4 v = *(const float4*)(in + i);
  out[i + 0] = (__bf16)v.x;
  out[i + 1] = (__bf16)v.y;
  out[i + 2] = (__bf16)v.z;
  out[i + 3] = (__bf16)v.w;
}

// ------------------------------------------- transpose fp32 [K][N] -> bf16 [N][K]
__global__ __launch_bounds__(256) void transpose_conv_kernel(const float* __restrict__ in,
                                                             __bf16* __restrict__ out,
                                                             int K, int N) {
  __shared__ float tile[32][33];
  const int n0 = blockIdx.x * 32, k0 = blockIdx.y * 32;
  const int tx = threadIdx.x, ty = threadIdx.y;  // (32, 8)
#pragma unroll
  for (int i = 0; i < 4; ++i)
    tile[ty * 4 + i][tx] = in[(size_t)(k0 + ty * 4 + i) * N + n0 + tx];
  __syncthreads();
#pragma unroll
  for (int i = 0; i < 4; ++i)
    out[(size_t)(n0 + ty * 4 + i) * K + k0 + tx] = (__bf16)tile[tx][ty * 4 + i];
}

// ------------------------------------------------------- rel-pos bias gather (TRANSPOSED)
// biasT[h][j][i] = table[ids[i*256+j]*12 + h]  -> attn reads f32x4 along i
__global__ __launch_bounds__(256) void bias_gather_kernel(const float* __restrict__ table,
                                                          const int* __restrict__ ids,
                                                          float* __restrict__ biasT) {
  const int idx = blockIdx.x * 256 + threadIdx.x;  // h*65536 + j*256 + i
  const int h = idx >> 16, ji = idx & 65535;
  const int j = ji >> 8, i = ji & 255;
  biasT[idx] = table[ids[i * 256 + j] * 12 + h];
}

// ---------------------------------------------------------------- bf16 GEMM (unchanged, round-2 verified)
// C[M,N] = A[M,K] * Bt^T. 128x128 tile, BK=64, 4 waves each 64x64.
// MODE 0: TRANS -> packed Q(scaled)/K scatter [b,h,n,d]; MODE 1: TRANS -> fp32 C+bias;
// MODE 2: no-TRANS -> packed V^T scatter [b,h,d,n]
template <int MODE>
__global__ __launch_bounds__(256) void gemm_kernel(const __bf16* __restrict__ A,
                                                   const __bf16* __restrict__ Bt,
                                                   const float* __restrict__ bias,
                                                   void* __restrict__ out0,
                                                   __bf16* __restrict__ kbuf,
                                                   const int M, const int N, const int K) {
  constexpr bool TRANS = (MODE != 2);
  __shared__ __bf16 smem[2 * 128 * 64];  // 32 KB
  const int tid = threadIdx.x;
  const int lane = tid & 63, w = tid >> 6;
  const int m16 = lane & 15, q4 = lane >> 4;
  const int wm = w & 1, wn = w >> 1;
  const int m0 = blockIdx.y * 128, n0 = blockIdx.x * 128;

  const __bf16* ag[4];
  const __bf16* bg[4];
  __bf16* la[4];
  __bf16* lb[4];
#pragma unroll
  for (int i = 0; i < 4; ++i) {
    const int row = w * 32 + i * 8 + (lane >> 3);
    const int col = ((lane & 7) ^ (row & 7)) * 8;
    ag[i] = A + (size_t)(m0 + row) * K + col;
    bg[i] = Bt + (size_t)(n0 + row) * K + col;
    la[i] = &smem[(w * 32 + i * 8) * 64];
    lb[i] = &smem[8192 + (w * 32 + i * 8) * 64];
  }

  int aoff[4][2], boff[4][2];
#pragma unroll
  for (int t = 0; t < 4; ++t)
#pragma unroll
    for (int kh = 0; kh < 2; ++kh) {
      const int ra = wm * 64 + t * 16 + m16;
      aoff[t][kh] = ra * 64 + (((kh * 4 + q4) ^ (ra & 7)) * 8);
      const int rb = wn * 64 + t * 16 + m16;
      boff[t][kh] = 8192 + rb * 64 + (((kh * 4 + q4) ^ (rb & 7)) * 8);
    }

  f32x4 acc[4][4] = {};
  const int ksteps = K >> 6;
  for (int kt = 0; kt < ksteps; ++kt) {
#pragma unroll
    for (int i = 0; i < 4; ++i) gload_lds16(ag[i], la[i]);
#pragma unroll
    for (int i = 0; i < 4; ++i) gload_lds16(bg[i], lb[i]);
#pragma unroll
    for (int i = 0; i < 4; ++i) { ag[i] += 64; bg[i] += 64; }
    __syncthreads();
    bf16x8 af[4][2], bfr[4][2];
#pragma unroll
    for (int t = 0; t < 4; ++t)
#pragma unroll
      for (int kh = 0; kh < 2; ++kh) {
        af[t][kh] = *(const bf16x8*)&smem[aoff[t][kh]];
        bfr[t][kh] = *(const bf16x8*)&smem[boff[t][kh]];
      }
#pragma unroll
    for (int kh = 0; kh < 2; ++kh)
#pragma unroll
      for (int i = 0; i < 4; ++i)
#pragma unroll
        for (int j = 0; j < 4; ++j) {
          if (TRANS)
            acc[i][j] = MFMA16(bfr[i][kh], af[j][kh], acc[i][j]);
          else
            acc[i][j] = MFMA16(af[i][kh], bfr[j][kh], acc[i][j]);
        }
    __syncthreads();
  }

  const int gnb = n0 + wn * 64;
  const int gmb = m0 + wm * 64;

  if (MODE == 0) {
    __bf16* qb = (__bf16*)out0;
    const int which = (n0 >= 768);
    __bf16* dst = which ? kbuf : qb;
    const float qscale = which ? 1.0f : 0.125f;
    const int bi = gmb >> 8;
    const int tokb = gmb & 255;
#pragma unroll
    for (int i = 0; i < 4; ++i) {
      const int gn0 = gnb + i * 16 + q4 * 4;
      const f32x4 bn = *(const f32x4*)&bias[gn0];
      const int rem0 = gn0 - which * 768;
      const int hh = rem0 >> 6, dd0 = rem0 & 63;
      __bf16* base = dst + ((size_t)bi * 12 + hh) * 16384 + dd0;
#pragma unroll
      for (int j = 0; j < 4; ++j) {
        const int tok = tokb + j * 16 + m16;
        bf16x4 pk;
#pragma unroll
        for (int r = 0; r < 4; ++r) pk[r] = (__bf16)((acc[i][j][r] + bn[r]) * qscale);
        *(bf16x4*)(base + (size_t)tok * 64) = pk;
      }
    }
  } else if (MODE == 2) {
    __bf16* vt = (__bf16*)out0;
    const int bi = gmb >> 8;
    const int tokb = gmb & 255;
#pragma unroll
    for (int j = 0; j < 4; ++j) {
      const int gn = gnb + j * 16 + m16;
      const float bn = bias[gn];
      const int hh = gn >> 6, dd = gn & 63;
      __bf16* base = vt + (((size_t)bi * 12 + hh) * 64 + dd) * 256;
#pragma unroll
      for (int i = 0; i < 4; ++i) {
        const int tok0 = tokb + i * 16 + q4 * 4;
        bf16x4 pk;
#pragma unroll
        for (int r = 0; r < 4; ++r) pk[r] = (__bf16)(acc[i][j][r] + bn);
        *(bf16x4*)(base + tok0) = pk;
      }
    }
  } else {
    float* out = (float*)out0;
#pragma unroll
    for (int i = 0; i < 4; ++i) {
      const int gn0 = gnb + i * 16 + q4 * 4;
      const f32x4 bn = *(const f32x4*)&bias[gn0];
#pragma unroll
      for (int j = 0; j < 4; ++j) {
        const int gm = gmb + j * 16 + m16;
        f32x4 v;
#pragma unroll
        for (int r = 0; r < 4; ++r) v[r] = acc[i][j][r] + bn[r];
        *(f32x4*)(out + (size_t)gm * N + gn0) = v;
      }
    }
  }
}

// ---------------------------------------------------------------- attention (rewritten)
// grid (2, 12, 128), block 512 = 8 waves; wave w owns 16 Q-rows.
// K [256x64] and V^T [64x256] staged in LDS (XOR-group swizzle, 2-way max bank alias).
// P round-trip reuses the K LDS region after a barrier.
__global__ __launch_bounds__(512, 4) void attn_kernel(const __bf16* __restrict__ qb,
                                                      const __bf16* __restrict__ kb,
                                                      const __bf16* __restrict__ vtb,
                                                      const float* __restrict__ biasT,
                                                      __bf16* __restrict__ o_ws) {
  __shared__ __bf16 klds[256 * 64];  // 32 KB, reused for P after S-phase
  __shared__ __bf16 vlds[64 * 256];  // 32 KB
  const int tid = threadIdx.x;
  const int lane = tid & 63, w = tid >> 6;  // w in [0,8)
  const int m16 = lane & 15, q4 = lane >> 4;
  const int h = blockIdx.y, b = blockIdx.z;
  const size_t bh = (size_t)b * 12 + h;
  const __bf16* Q = qb + bh * (256 * 64);
  const __bf16* Kp = kb + bh * (256 * 64);
  const __bf16* Vt = vtb + bh * (64 * 256);
  const float* BhT = biasT + (size_t)h * 65536;
  const int qbase = blockIdx.x * 128;
  const int qrow0 = qbase + w * 16;  // this wave's 16 Q-rows

  // --- stage K: wave w covers rows [w*32, w*32+32), 4 insts x 8 rows x 128 B
#pragma unroll
  for (int i = 0; i < 4; ++i) {
    const int row = w * 32 + i * 8 + (lane >> 3);
    const int col = ((lane & 7) ^ (row & 7)) * 8;
    gload_lds16(Kp + (size_t)row * 64 + col, &klds[(w * 32 + i * 8) * 64]);
  }
  // --- stage V^T: wave w covers rows [w*8, w*8+8), 4 insts x 2 rows x 512 B
#pragma unroll
  for (int i = 0; i < 4; ++i) {
    const int row = w * 8 + i * 2 + (lane >> 5);
    const int g = lane & 31;
    const int gp = (g & 24) | ((g & 7) ^ (row & 7));
    gload_lds16(Vt + (size_t)row * 256 + gp * 8, &vlds[(w * 8 + i * 2) * 256]);
  }

  // --- Q frags (A-layout) from global, overlaps staging
  bf16x8 qf[2];
#pragma unroll
  for (int t = 0; t < 2; ++t)
    qf[t] = *(const bf16x8*)(Q + (size_t)(qrow0 + m16) * 64 + t * 32 + q4 * 8);

  __syncthreads();  // staging complete (barrier drains vmcnt)

  // --- S = (Q*scale) K^T from LDS
  f32x4 s[16];
#pragma unroll
  for (int c = 0; c < 16; ++c) {
    const int krow = c * 16 + m16;
    const bf16x8 kf0 = *(const bf16x8*)&klds[krow * 64 + ((q4 ^ (m16 & 7)) * 8)];
    const bf16x8 kf1 = *(const bf16x8*)&klds[krow * 64 + (((4 + q4) ^ (m16 & 7)) * 8)];
    f32x4 z = {0.f, 0.f, 0.f, 0.f};
    z = MFMA16(qf[0], kf0, z);
    s[c] = MFMA16(qf[1], kf1, z);
  }

  // --- + rel-pos bias, f32x4 along the q-row dim (transposed gather layout)
#pragma unroll
  for (int c = 0; c < 16; ++c) {
    const f32x4 bv = *(const f32x4*)&BhT[(size_t)(c * 16 + m16) * 256 + qrow0 + q4 * 4];
    s[c] += bv;
  }

  // --- full-row softmax; row owned by the 16 lanes sharing q4
  float linv[4];
#pragma unroll
  for (int r = 0; r < 4; ++r) {
    float mx = s[0][r];
#pragma unroll
    for (int c = 1; c < 16; ++c) mx = fmaxf(mx, s[c][r]);
    mx = fmaxf(mx, __shfl_xor(mx, 1));
    mx = fmaxf(mx, __shfl_xor(mx, 2));
    mx = fmaxf(mx, __shfl_xor(mx, 4));
    mx = fmaxf(mx, __shfl_xor(mx, 8));
    float sum = 0.f;
#pragma unroll
    for (int c = 0; c < 16; ++c) {
      const float p = exp2f((s[c][r] - mx) * 1.4426950408889634f);
      s[c][r] = p;
      sum += p;
    }
    sum += __shfl_xor(sum, 1);
    sum += __shfl_xor(sum, 2);
    sum += __shfl_xor(sum, 4);
    sum += __shfl_xor(sum, 8);
    linv[r] = 1.f / sum;
  }

  __syncthreads();  // all K ds_reads done before P overwrites the K region

  // --- O = P V; P round-trips through per-wave slice of the K region
  f32x4 o[4] = {};
  __bf16* P = &klds[w * 1152];  // 16 rows x 72 elems (16-B aligned rows)
#pragma unroll
  for (int ch = 0; ch < 4; ++ch) {
#pragma unroll
    for (int cc = 0; cc < 4; ++cc)
#pragma unroll
      for (int r = 0; r < 4; ++r)
        P[(q4 * 4 + r) * 72 + cc * 16 + m16] = (__bf16)s[ch * 4 + cc][r];
    // same-wave LDS RAW/WAR: compiler lgkmcnt waits, no barrier needed
#pragma unroll
    for (int kt = 0; kt < 2; ++kt) {
      const bf16x8 pf = *(const bf16x8*)(P + m16 * 72 + kt * 32 + q4 * 8);
#pragma unroll
      for (int dt = 0; dt < 4; ++dt) {
        const int vrow = dt * 16 + m16;
        const bf16x8 vf = *(const bf16x8*)&vlds[vrow * 256 + ch * 64 +
                                                (((kt * 4 + q4) ^ (m16 & 7)) * 8)];
        o[dt] = MFMA16(pf, vf, o[dt]);
      }
    }
  }

  // --- normalize + store bf16 [b*n][h*64+d] for the out-proj GEMM
#pragma unroll
  for (int dt = 0; dt < 4; ++dt)
#pragma unroll
    for (int r = 0; r < 4; ++r) {
      const float v = o[dt][r] * linv[r];
      const size_t row = (size_t)b * 256 + qrow0 + q4 * 4 + r;
      o_ws[row * 768 + h * 64 + dt * 16 + m16] = (__bf16)v;
    }
}

// ---------------------------------------------------------------- launch
extern "C" void kernel_launch(void* const* d_in, const int* in_sizes, int n_in,
                              void* d_out, int out_size, void* d_ws, size_t ws_size,
                              hipStream_t stream) {
  const float* x = (const float*)d_in[0];      // [128,256,768]
  const float* Wqkv = (const float*)d_in[1];   // [768,2304]
  const float* bqkv = (const float*)d_in[2];   // [2304]
  const float* Wout = (const float*)d_in[3];   // [768,768]
  const float* bout = (const float*)d_in[4];   // [768]
  const float* table = (const float*)d_in[5];  // [961,12]
  const int* ids = (const int*)d_in[6];        // [65536]
  float* out = (float*)d_out;

  char* ws = (char*)d_ws;
  __bf16* xbf = (__bf16*)ws;                             // 50331648 B (alias: o_ws)
  __bf16* wqkvt = (__bf16*)(ws + 50331648);              //  3538944 B
  __bf16* woutt = (__bf16*)(ws + 53870592);              //  1179648 B
  __bf16* qbuf = (__bf16*)(ws + 55050240);               // 50331648 B
  __bf16* kbuf = (__bf16*)(ws + 105381888);              // 50331648 B
  __bf16* vtbuf = (__bf16*)(ws + 155713536);             // 50331648 B
  float* biasT = (float*)(ws + 206045184);               //  3145728 B

  conv_x_kernel<<<24576, 256, 0, stream>>>(x, xbf);
  transpose_conv_kernel<<<dim3(72, 24), dim3(32, 8), 0, stream>>>(Wqkv, wqkvt, 768, 2304);
  transpose_conv_kernel<<<dim3(24, 24), dim3(32, 8), 0, stream>>>(Wout, woutt, 768, 768);
  bias_gather_kernel<<<3072, 256, 0, stream>>>(table, ids, biasT);
  gemm_kernel<0><<<dim3(12, 256), 256, 0, stream>>>(xbf, wqkvt, bqkv, qbuf, kbuf,
                                                    32768, 2304, 768);
  gemm_kernel<2><<<dim3(6, 256), 256, 0, stream>>>(xbf, wqkvt + (size_t)1536 * 768,
                                                   bqkv + 1536, vtbuf, nullptr,
                                                   32768, 768, 768);
  attn_kernel<<<dim3(2, 12, 128), 512, 0, stream>>>(qbuf, kbuf, vtbuf, biasT, xbf /*o_ws*/);
  gemm_kernel<1><<<dim3(6, 256), 256, 0, stream>>>(xbf, woutt, bout, out, nullptr,
                                                   32768, 768, 768);
}

// Round 4
// 481.555 us; speedup vs baseline: 1.3130x; 1.0969x over previous
//
#include <hip/hip_runtime.h>
#include <cstdint>
#include <cstddef>

typedef __bf16 bf16x8 __attribute__((ext_vector_type(8)));
typedef __bf16 bf16x4 __attribute__((ext_vector_type(4)));
typedef float f32x4 __attribute__((ext_vector_type(4)));
static_assert(sizeof(bf16x8) == 16, "bf16x8 must be 16B");
static_assert(sizeof(bf16x4) == 8, "bf16x4 must be 8B");
static_assert(sizeof(f32x4) == 16, "f32x4 must be 16B");

#define MFMA16(a, b, c) __builtin_amdgcn_mfma_f32_16x16x32_bf16((a), (b), (c), 0, 0, 0)

__device__ __forceinline__ void gload_lds16(const void* g, void* l) {
  __builtin_amdgcn_global_load_lds(
      (const __attribute__((address_space(1))) void*)g,
      (__attribute__((address_space(3))) void*)l, 16, 0, 0);
}

// ---------------------------------------------------------------- conv x -> bf16
__global__ __launch_bounds__(256) void conv_x_kernel(const float* __restrict__ in,
                                                     __bf16* __restrict__ out) {
  size_t i = ((size_t)blockIdx.x * 256 + threadIdx.x) * 4;
  const float4 v = *(const float4*)(in + i);
  out[i + 0] = (__bf16)v.x;
  out[i + 1] = (__bf16)v.y;
  out[i + 2] = (__bf16)v.z;
  out[i + 3] = (__bf16)v.w;
}

// ------------------------------------------- transpose fp32 [K][N] -> bf16 [N][K]
__global__ __launch_bounds__(256) void transpose_conv_kernel(const float* __restrict__ in,
                                                             __bf16* __restrict__ out,
                                                             int K, int N) {
  __shared__ float tile[32][33];
  const int n0 = blockIdx.x * 32, k0 = blockIdx.y * 32;
  const int tx = threadIdx.x, ty = threadIdx.y;  // (32, 8)
#pragma unroll
  for (int i = 0; i < 4; ++i)
    tile[ty * 4 + i][tx] = in[(size_t)(k0 + ty * 4 + i) * N + n0 + tx];
  __syncthreads();
#pragma unroll
  for (int i = 0; i < 4; ++i)
    out[(size_t)(n0 + ty * 4 + i) * K + k0 + tx] = (__bf16)tile[tx][ty * 4 + i];
}

// ------------------------------------------------------- rel-pos bias gather (TRANSPOSED)
// biasT[h][j][i] = table[ids[i*256+j]*12 + h]  -> attn reads f32x4 along i
__global__ __launch_bounds__(256) void bias_gather_kernel(const float* __restrict__ table,
                                                          const int* __restrict__ ids,
                                                          float* __restrict__ biasT) {
  const int idx = blockIdx.x * 256 + threadIdx.x;  // h*65536 + j*256 + i
  const int h = idx >> 16, ji = idx & 65535;
  const int j = ji >> 8, i = ji & 255;
  biasT[idx] = table[ids[i * 256 + j] * 12 + h];
}

// ---------------------------------------------------------------- bf16 GEMM
// C[M,N] = A[M,K] * Bt^T. 128x128 tile, BK=64, 4 waves each 64x64.
// 1-D grid with panel/XCD swizzle: mi=id&7, ny=(id>>3)%NT, g=id/(8*NT);
// m0=(g*8+mi)*128 -> the NT blocks sharing an A-tile have ids differing by 8
// = same XCD; per-XCD resident set ~8 A-tiles + all B ~= L2 capacity.
// MODE 0: TRANS -> packed Q(scaled)/K scatter [b,h,n,d]; MODE 1: TRANS -> fp32 C+bias;
// MODE 2: no-TRANS -> packed V^T scatter [b,h,d,n]
template <int MODE, int NT>
__global__ __launch_bounds__(256) void gemm_kernel(const __bf16* __restrict__ A,
                                                   const __bf16* __restrict__ Bt,
                                                   const float* __restrict__ bias,
                                                   void* __restrict__ out0,
                                                   __bf16* __restrict__ kbuf,
                                                   const int M, const int N, const int K) {
  constexpr bool TRANS = (MODE != 2);
  __shared__ __bf16 smem[2 * 128 * 64];  // 32 KB
  const int tid = threadIdx.x;
  const int lane = tid & 63, w = tid >> 6;
  const int m16 = lane & 15, q4 = lane >> 4;
  const int wm = w & 1, wn = w >> 1;
  const int id = blockIdx.x;
  const int mi = id & 7;
  const int rest = id >> 3;
  const int ny = rest % NT;
  const int g = rest / NT;
  const int m0 = (g * 8 + mi) * 128;
  const int n0 = ny * 128;

  const __bf16* ag[4];
  const __bf16* bg[4];
  __bf16* la[4];
  __bf16* lb[4];
#pragma unroll
  for (int i = 0; i < 4; ++i) {
    const int row = w * 32 + i * 8 + (lane >> 3);
    const int col = ((lane & 7) ^ (row & 7)) * 8;
    ag[i] = A + (size_t)(m0 + row) * K + col;
    bg[i] = Bt + (size_t)(n0 + row) * K + col;
    la[i] = &smem[(w * 32 + i * 8) * 64];
    lb[i] = &smem[8192 + (w * 32 + i * 8) * 64];
  }

  int aoff[4][2], boff[4][2];
#pragma unroll
  for (int t = 0; t < 4; ++t)
#pragma unroll
    for (int kh = 0; kh < 2; ++kh) {
      const int ra = wm * 64 + t * 16 + m16;
      aoff[t][kh] = ra * 64 + (((kh * 4 + q4) ^ (ra & 7)) * 8);
      const int rb = wn * 64 + t * 16 + m16;
      boff[t][kh] = 8192 + rb * 64 + (((kh * 4 + q4) ^ (rb & 7)) * 8);
    }

  f32x4 acc[4][4] = {};
  const int ksteps = K >> 6;
  for (int kt = 0; kt < ksteps; ++kt) {
#pragma unroll
    for (int i = 0; i < 4; ++i) gload_lds16(ag[i], la[i]);
#pragma unroll
    for (int i = 0; i < 4; ++i) gload_lds16(bg[i], lb[i]);
#pragma unroll
    for (int i = 0; i < 4; ++i) { ag[i] += 64; bg[i] += 64; }
    __syncthreads();
    bf16x8 af[4][2], bfr[4][2];
#pragma unroll
    for (int t = 0; t < 4; ++t)
#pragma unroll
      for (int kh = 0; kh < 2; ++kh) {
        af[t][kh] = *(const bf16x8*)&smem[aoff[t][kh]];
        bfr[t][kh] = *(const bf16x8*)&smem[boff[t][kh]];
      }
#pragma unroll
    for (int kh = 0; kh < 2; ++kh)
#pragma unroll
      for (int i = 0; i < 4; ++i)
#pragma unroll
        for (int j = 0; j < 4; ++j) {
          if (TRANS)
            acc[i][j] = MFMA16(bfr[i][kh], af[j][kh], acc[i][j]);
          else
            acc[i][j] = MFMA16(af[i][kh], bfr[j][kh], acc[i][j]);
        }
    __syncthreads();
  }

  const int gnb = n0 + wn * 64;
  const int gmb = m0 + wm * 64;

  if (MODE == 0) {
    __bf16* qb = (__bf16*)out0;
    const int which = (n0 >= 768);
    __bf16* dst = which ? kbuf : qb;
    const float qscale = which ? 1.0f : 0.125f;
    const int bi = gmb >> 8;
    const int tokb = gmb & 255;
#pragma unroll
    for (int i = 0; i < 4; ++i) {
      const int gn0 = gnb + i * 16 + q4 * 4;
      const f32x4 bn = *(const f32x4*)&bias[gn0];
      const int rem0 = gn0 - which * 768;
      const int hh = rem0 >> 6, dd0 = rem0 & 63;
      __bf16* base = dst + ((size_t)bi * 12 + hh) * 16384 + dd0;
#pragma unroll
      for (int j = 0; j < 4; ++j) {
        const int tok = tokb + j * 16 + m16;
        bf16x4 pk;
#pragma unroll
        for (int r = 0; r < 4; ++r) pk[r] = (__bf16)((acc[i][j][r] + bn[r]) * qscale);
        *(bf16x4*)(base + (size_t)tok * 64) = pk;
      }
    }
  } else if (MODE == 2) {
    __bf16* vt = (__bf16*)out0;
    const int bi = gmb >> 8;
    const int tokb = gmb & 255;
#pragma unroll
    for (int j = 0; j < 4; ++j) {
      const int gn = gnb + j * 16 + m16;
      const float bn = bias[gn];
      const int hh = gn >> 6, dd = gn & 63;
      __bf16* base = vt + (((size_t)bi * 12 + hh) * 64 + dd) * 256;
#pragma unroll
      for (int i = 0; i < 4; ++i) {
        const int tok0 = tokb + i * 16 + q4 * 4;
        bf16x4 pk;
#pragma unroll
        for (int r = 0; r < 4; ++r) pk[r] = (__bf16)(acc[i][j][r] + bn);
        *(bf16x4*)(base + tok0) = pk;
      }
    }
  } else {
    float* out = (float*)out0;
#pragma unroll
    for (int i = 0; i < 4; ++i) {
      const int gn0 = gnb + i * 16 + q4 * 4;
      const f32x4 bn = *(const f32x4*)&bias[gn0];
#pragma unroll
      for (int j = 0; j < 4; ++j) {
        const int gm = gmb + j * 16 + m16;
        f32x4 v;
#pragma unroll
        for (int r = 0; r < 4; ++r) v[r] = acc[i][j][r] + bn[r];
        *(f32x4*)(out + (size_t)gm * N + gn0) = v;
      }
    }
  }
}

// ---------------------------------------------------------------- attention
// grid (128, 12, 2): b, h, half — the two halves sharing (b,h) K/V differ by
// 1536 linear ids (=0 mod 8) -> same XCD, second half L2-hits K/V.
// block 512 = 8 waves; wave w owns 16 Q-rows. K and V^T staged in LDS
// (XOR-group swizzle). P round-trip reuses the K LDS region after a barrier.
__global__ __launch_bounds__(512, 4) void attn_kernel(const __bf16* __restrict__ qb,
                                                      const __bf16* __restrict__ kb,
                                                      const __bf16* __restrict__ vtb,
                                                      const float* __restrict__ biasT,
                                                      __bf16* __restrict__ o_ws) {
  __shared__ __bf16 klds[256 * 64];  // 32 KB, reused for P after S-phase
  __shared__ __bf16 vlds[64 * 256];  // 32 KB
  const int tid = threadIdx.x;
  const int lane = tid & 63, w = tid >> 6;  // w in [0,8)
  const int m16 = lane & 15, q4 = lane >> 4;
  const int b = blockIdx.x, h = blockIdx.y;
  const size_t bh = (size_t)b * 12 + h;
  const __bf16* Q = qb + bh * (256 * 64);
  const __bf16* Kp = kb + bh * (256 * 64);
  const __bf16* Vt = vtb + bh * (64 * 256);
  const float* BhT = biasT + (size_t)h * 65536;
  const int qbase = blockIdx.z * 128;
  const int qrow0 = qbase + w * 16;  // this wave's 16 Q-rows

  // --- stage K: wave w covers rows [w*32, w*32+32), 4 insts x 8 rows x 128 B
#pragma unroll
  for (int i = 0; i < 4; ++i) {
    const int row = w * 32 + i * 8 + (lane >> 3);
    const int col = ((lane & 7) ^ (row & 7)) * 8;
    gload_lds16(Kp + (size_t)row * 64 + col, &klds[(w * 32 + i * 8) * 64]);
  }
  // --- stage V^T: wave w covers rows [w*8, w*8+8), 4 insts x 2 rows x 512 B
#pragma unroll
  for (int i = 0; i < 4; ++i) {
    const int row = w * 8 + i * 2 + (lane >> 5);
    const int g = lane & 31;
    const int gp = (g & 24) | ((g & 7) ^ (row & 7));
    gload_lds16(Vt + (size_t)row * 256 + gp * 8, &vlds[(w * 8 + i * 2) * 256]);
  }

  // --- Q frags (A-layout) from global, overlaps staging
  bf16x8 qf[2];
#pragma unroll
  for (int t = 0; t < 2; ++t)
    qf[t] = *(const bf16x8*)(Q + (size_t)(qrow0 + m16) * 64 + t * 32 + q4 * 8);

  __syncthreads();  // staging complete (barrier drains vmcnt)

  // --- S = (Q*scale) K^T from LDS
  f32x4 s[16];
#pragma unroll
  for (int c = 0; c < 16; ++c) {
    const int krow = c * 16 + m16;
    const bf16x8 kf0 = *(const bf16x8*)&klds[krow * 64 + ((q4 ^ (m16 & 7)) * 8)];
    const bf16x8 kf1 = *(const bf16x8*)&klds[krow * 64 + (((4 + q4) ^ (m16 & 7)) * 8)];
    f32x4 z = {0.f, 0.f, 0.f, 0.f};
    z = MFMA16(qf[0], kf0, z);
    s[c] = MFMA16(qf[1], kf1, z);
  }

  // --- + rel-pos bias, f32x4 along the q-row dim (transposed gather layout)
#pragma unroll
  for (int c = 0; c < 16; ++c) {
    const f32x4 bv = *(const f32x4*)&BhT[(size_t)(c * 16 + m16) * 256 + qrow0 + q4 * 4];
    s[c] += bv;
  }

  // --- full-row softmax; row owned by the 16 lanes sharing q4
  float linv[4];
#pragma unroll
  for (int r = 0; r < 4; ++r) {
    float mx = s[0][r];
#pragma unroll
    for (int c = 1; c < 16; ++c) mx = fmaxf(mx, s[c][r]);
    mx = fmaxf(mx, __shfl_xor(mx, 1));
    mx = fmaxf(mx, __shfl_xor(mx, 2));
    mx = fmaxf(mx, __shfl_xor(mx, 4));
    mx = fmaxf(mx, __shfl_xor(mx, 8));
    float sum = 0.f;
#pragma unroll
    for (int c = 0; c < 16; ++c) {
      const float p = exp2f((s[c][r] - mx) * 1.4426950408889634f);
      s[c][r] = p;
      sum += p;
    }
    sum += __shfl_xor(sum, 1);
    sum += __shfl_xor(sum, 2);
    sum += __shfl_xor(sum, 4);
    sum += __shfl_xor(sum, 8);
    linv[r] = 1.f / sum;
  }

  __syncthreads();  // all K ds_reads done before P overwrites the K region

  // --- O = P V; P round-trips through per-wave slice of the K region
  f32x4 o[4] = {};
  __bf16* P = &klds[w * 1152];  // 16 rows x 72 elems (16-B aligned rows)
#pragma unroll
  for (int ch = 0; ch < 4; ++ch) {
#pragma unroll
    for (int cc = 0; cc < 4; ++cc)
#pragma unroll
      for (int r = 0; r < 4; ++r)
        P[(q4 * 4 + r) * 72 + cc * 16 + m16] = (__bf16)s[ch * 4 + cc][r];
    // same-wave LDS RAW/WAR: compiler lgkmcnt waits, no barrier needed
#pragma unroll
    for (int kt = 0; kt < 2; ++kt) {
      const bf16x8 pf = *(const bf16x8*)(P + m16 * 72 + kt * 32 + q4 * 8);
#pragma unroll
      for (int dt = 0; dt < 4; ++dt) {
        const int vrow = dt * 16 + m16;
        const bf16x8 vf = *(const bf16x8*)&vlds[vrow * 256 + ch * 64 +
                                                (((kt * 4 + q4) ^ (m16 & 7)) * 8)];
        o[dt] = MFMA16(pf, vf, o[dt]);
      }
    }
  }

  // --- normalize + store bf16 [b*n][h*64+d] for the out-proj GEMM
#pragma unroll
  for (int dt = 0; dt < 4; ++dt)
#pragma unroll
    for (int r = 0; r < 4; ++r) {
      const float v = o[dt][r] * linv[r];
      const size_t row = (size_t)b * 256 + qrow0 + q4 * 4 + r;
      o_ws[row * 768 + h * 64 + dt * 16 + m16] = (__bf16)v;
    }
}

// ---------------------------------------------------------------- launch
extern "C" void kernel_launch(void* const* d_in, const int* in_sizes, int n_in,
                              void* d_out, int out_size, void* d_ws, size_t ws_size,
                              hipStream_t stream) {
  const float* x = (const float*)d_in[0];      // [128,256,768]
  const float* Wqkv = (const float*)d_in[1];   // [768,2304]
  const float* bqkv = (const float*)d_in[2];   // [2304]
  const float* Wout = (const float*)d_in[3];   // [768,768]
  const float* bout = (const float*)d_in[4];   // [768]
  const float* table = (const float*)d_in[5];  // [961,12]
  const int* ids = (const int*)d_in[6];        // [65536]
  float* out = (float*)d_out;

  char* ws = (char*)d_ws;
  __bf16* xbf = (__bf16*)ws;                             // 50331648 B (alias: o_ws)
  __bf16* wqkvt = (__bf16*)(ws + 50331648);              //  3538944 B
  __bf16* woutt = (__bf16*)(ws + 53870592);              //  1179648 B
  __bf16* qbuf = (__bf16*)(ws + 55050240);               // 50331648 B
  __bf16* kbuf = (__bf16*)(ws + 105381888);              // 50331648 B
  __bf16* vtbuf = (__bf16*)(ws + 155713536);             // 50331648 B
  float* biasT = (float*)(ws + 206045184);               //  3145728 B

  conv_x_kernel<<<24576, 256, 0, stream>>>(x, xbf);
  transpose_conv_kernel<<<dim3(72, 24), dim3(32, 8), 0, stream>>>(Wqkv, wqkvt, 768, 2304);
  transpose_conv_kernel<<<dim3(24, 24), dim3(32, 8), 0, stream>>>(Wout, woutt, 768, 768);
  bias_gather_kernel<<<3072, 256, 0, stream>>>(table, ids, biasT);
  // QK part: N in [0,1536), 12 N-tiles, 256 M-tiles -> 3072 blocks (panel-swizzled)
  gemm_kernel<0, 12><<<3072, 256, 0, stream>>>(xbf, wqkvt, bqkv, qbuf, kbuf,
                                               32768, 2304, 768);
  // V part: N in [1536,2304) -> V^T scatter, 6 N-tiles -> 1536 blocks
  gemm_kernel<2, 6><<<1536, 256, 0, stream>>>(xbf, wqkvt + (size_t)1536 * 768,
                                              bqkv + 1536, vtbuf, nullptr,
                                              32768, 768, 768);
  attn_kernel<<<dim3(128, 12, 2), 512, 0, stream>>>(qbuf, kbuf, vtbuf, biasT, xbf /*o_ws*/);
  gemm_kernel<1, 6><<<1536, 256, 0, stream>>>(xbf, woutt, bout, out, nullptr,
                                              32768, 768, 768);
}